// Round 7
// baseline (358.989 us; speedup 1.0000x reference)
//
#include <hip/hip_runtime.h>

// HalfEdgeMeshPool: segment-mean over groups.
// feat: [B, C, N] f32, gid: [B, N] i32 in [0,T), out: [B, C, T] f32.
//
// R1/R2: LDS f32 atomics serialize ~3.2 cyc/lane -> 428us floor.
// R3: random 4B global gather = 14.5x line over-fetch -> 1.7ms.
// R5/R6: sort + bf16 transpose + sequential reduce -> 250us; limited by the
//        820 MB total traffic (featT 164MB round-trip at scattered 512B).
// R7: fuse everything. One block per (b,c) row: stream row -> LDS bf16 (80KB),
//     permute into sorted order inside LDS (val, 80KB), per-group sum + write.
//     HBM traffic = 328 (feat) + 164 (out) + ~12 MB (perm via L2) ~= 504 MB.
//     Random access confined to LDS; all global access sequential/coalesced.
static constexpr int B = 8;
static constexpr int C = 256;
static constexpr int N = 40000;
static constexpr int T = 20000;
static constexpr int RPS = T + 4;    // rp row stride (int4 alignment per b)

typedef float  f32x4 __attribute__((ext_vector_type(4)));
typedef int    i32x4 __attribute__((ext_vector_type(4)));
typedef ushort u16x4 __attribute__((ext_vector_type(4)));

__device__ __forceinline__ ushort f2bf(float v) {
    unsigned u = __float_as_uint(v);
    u += 0x7FFFu + ((u >> 16) & 1u);  // round-to-nearest-even
    return (ushort)(u >> 16);
}
__device__ __forceinline__ float bf2f(ushort u) {
    return __uint_as_float((unsigned)u << 16);
}

// ---- zero counts ----
__global__ void __launch_bounds__(256) hemp_zero_kernel(int* __restrict__ counts) {
    int i = blockIdx.x * 256 + threadIdx.x;
    if (i < B * T / 4) reinterpret_cast<int4*>(counts)[i] = make_int4(0, 0, 0, 0);
}

// ---- per-(b,t) member counts ----
__global__ void __launch_bounds__(256) hemp_count_kernel(const int* __restrict__ gid,
                                                         int* __restrict__ counts) {
    int idx = blockIdx.x * 256 + threadIdx.x;
    if (idx >= B * N / 4) return;
    int b = idx / (N / 4);
    int i4 = idx - b * (N / 4);
    int4 g = reinterpret_cast<const int4*>(gid + (size_t)b * N)[i4];
    int* cb = counts + b * T;
    atomicAdd(&cb[g.x], 1);
    atomicAdd(&cb[g.y], 1);
    atomicAdd(&cb[g.z], 1);
    atomicAdd(&cb[g.w], 1);
}

// ---- exclusive scan counts -> rp [B][RPS]; seed head = rp ----
__global__ void __launch_bounds__(1024) hemp_scan_kernel(const int* __restrict__ counts,
                                                         int* __restrict__ rp,
                                                         int* __restrict__ head) {
    const int b = blockIdx.x;
    __shared__ int wsum[16];
    __shared__ int carry_s, chunk_total_s;
    const int tid = threadIdx.x, lane = tid & 63, wv = tid >> 6;
    if (tid == 0) carry_s = 0;
    __syncthreads();
    const int4* c4 = reinterpret_cast<const int4*>(counts + (size_t)b * T);
    int4* rp4 = reinterpret_cast<int4*>(rp + (size_t)b * RPS);
    int4* hd4 = reinterpret_cast<int4*>(head + (size_t)b * T);
    constexpr int NI4 = T / 4;  // 5000
    for (int base = 0; base < NI4; base += 1024) {
        int i = base + tid;
        int4 x = (i < NI4) ? c4[i] : make_int4(0, 0, 0, 0);
        int s = x.x + x.y + x.z + x.w;
        int inc = s;
        #pragma unroll
        for (int off = 1; off < 64; off <<= 1) {
            int y = __shfl_up(inc, off);
            if (lane >= off) inc += y;
        }
        if (lane == 63) wsum[wv] = inc;
        __syncthreads();
        if (wv == 0 && lane < 16) {
            int w = wsum[lane];
            int winc = w;
            #pragma unroll
            for (int off = 1; off < 16; off <<= 1) {
                int y = __shfl_up(winc, off);
                if (lane >= off) winc += y;
            }
            wsum[lane] = winc - w;
            if (lane == 15) chunk_total_s = winc;
        }
        __syncthreads();
        int e = carry_s + wsum[wv] + (inc - s);
        if (i < NI4) {
            int4 r;
            r.x = e;
            r.y = e + x.x;
            r.z = r.y + x.y;
            r.w = r.z + x.z;
            rp4[i] = r;
            hd4[i] = r;
        }
        __syncthreads();
        if (tid == 0) carry_s += chunk_total_s;
        __syncthreads();
    }
    if (tid == 0) rp[(size_t)b * RPS + T] = N;
}

// ---- scatter n into perm (sorted-by-gid order) ----
__global__ void __launch_bounds__(256) hemp_fill_kernel(const int* __restrict__ gid,
                                                        int* __restrict__ head,
                                                        int* __restrict__ perm) {
    int idx = blockIdx.x * 256 + threadIdx.x;
    if (idx >= B * N / 4) return;
    int b = idx / (N / 4);
    int i4 = idx - b * (N / 4);
    int4 g = reinterpret_cast<const int4*>(gid + (size_t)b * N)[i4];
    int* hb = head + b * T;
    int* pb = perm + (size_t)b * N;
    int n = i4 * 4;
    pb[atomicAdd(&hb[g.x], 1)] = n + 0;
    pb[atomicAdd(&hb[g.y], 1)] = n + 1;
    pb[atomicAdd(&hb[g.z], 1)] = n + 2;
    pb[atomicAdd(&hb[g.w], 1)] = n + 3;
}

// ---- fused pool: one block per (b,c) row. row->LDS bf16, LDS permute, reduce ----
__global__ void __launch_bounds__(512, 1) hemp_fused_kernel(const float* __restrict__ feat,
                                                            const int* __restrict__ perm,
                                                            const int* __restrict__ rp,
                                                            float* __restrict__ out) {
    extern __shared__ ushort sh[];          // row_bf: [0,40960) u16, val: [40960,80960)
    ushort* __restrict__ row_bf = sh;
    ushort* __restrict__ val = sh + 40960;  // 81920 B offset; total 161920 B
    const int tid = threadIdx.x;
    const int b = blockIdx.x >> 8;  // blocks 0..255 all b=0 -> perm_b L2-hot
    const int c = blockIdx.x & 255;

    // Phase 1: stream feature row into LDS as bf16 (sequential, nontemporal)
    const f32x4* __restrict__ f4 =
        reinterpret_cast<const f32x4*>(feat + (size_t)(b * C + c) * N);
    for (int i = tid; i < N / 4; i += 512) {
        f32x4 v = __builtin_nontemporal_load(f4 + i);
        u16x4 w;
        w.x = f2bf(v.x);
        w.y = f2bf(v.y);
        w.z = f2bf(v.z);
        w.w = f2bf(v.w);
        *reinterpret_cast<u16x4*>(&row_bf[i * 4]) = w;
    }
    __syncthreads();

    // Phase 2: permute into sorted-by-group order inside LDS
    const i32x4* __restrict__ p4 = reinterpret_cast<const i32x4*>(perm + (size_t)b * N);
    for (int i = tid; i < N / 4; i += 512) {
        i32x4 p = p4[i];
        u16x4 w;
        w.x = row_bf[p.x];
        w.y = row_bf[p.y];
        w.z = row_bf[p.z];
        w.w = row_bf[p.w];
        *reinterpret_cast<u16x4*>(&val[i * 4]) = w;
    }
    __syncthreads();

    // Phase 3: per-group sequential sum + fused divide, coalesced write
    const int* __restrict__ rpb = rp + (size_t)b * RPS;
    float* __restrict__ orow = out + (size_t)(b * C + c) * T;
    for (int t = tid; t < T; t += 512) {
        const int js = rpb[t], je = rpb[t + 1];
        float s = 0.0f;
        for (int j = js; j < je; ++j) s += bf2f(val[j]);
        __builtin_nontemporal_store(s / fmaxf((float)(je - js), 1.0f), orow + t);
    }
}

// ---- fallback (ws too small): R2 LDS-atomic kernel ----
static constexpr int BLK = 1024;
__global__ void __launch_bounds__(BLK) hemp_atomic_kernel(const float* __restrict__ feat,
                                                          const int* __restrict__ gid,
                                                          const int* __restrict__ counts,
                                                          float* __restrict__ out) {
    extern __shared__ float lds_sum[];
    const int tid = threadIdx.x;
    const int b = blockIdx.x >> 8;
    const int c = blockIdx.x & 255;
    float4* ls4 = reinterpret_cast<float4*>(lds_sum);
    for (int t = tid; t < T / 4; t += BLK) ls4[t] = make_float4(0.f, 0.f, 0.f, 0.f);
    __syncthreads();
    const float4* f4 = reinterpret_cast<const float4*>(feat + (size_t)(b * C + c) * N);
    const int4* g4 = reinterpret_cast<const int4*>(gid + (size_t)b * N);
    for (int i = tid; i < N / 4; i += BLK) {
        float4 v = f4[i];
        int4 g = g4[i];
        unsafeAtomicAdd(&lds_sum[g.x], v.x);
        unsafeAtomicAdd(&lds_sum[g.y], v.y);
        unsafeAtomicAdd(&lds_sum[g.z], v.z);
        unsafeAtomicAdd(&lds_sum[g.w], v.w);
    }
    __syncthreads();
    const int4* cnt4 = reinterpret_cast<const int4*>(counts + (size_t)b * T);
    float4* out4 = reinterpret_cast<float4*>(out + (size_t)(b * C + c) * T);
    for (int t = tid; t < T / 4; t += BLK) {
        int4 cn = cnt4[t];
        float4 s = ls4[t];
        float4 r;
        r.x = s.x / fmaxf((float)cn.x, 1.0f);
        r.y = s.y / fmaxf((float)cn.y, 1.0f);
        r.z = s.z / fmaxf((float)cn.z, 1.0f);
        r.w = s.w / fmaxf((float)cn.w, 1.0f);
        out4[t] = r;
    }
}

extern "C" void kernel_launch(void* const* d_in, const int* in_sizes, int n_in,
                              void* d_out, int out_size, void* d_ws, size_t ws_size,
                              hipStream_t stream) {
    const float* feat = (const float*)d_in[0];
    const int* gid = (const int*)d_in[1];
    float* out = (float*)d_out;

    // ws: counts[B*T] | head[B*T] | rp[B*RPS] | perm[B*N]  (~2.5 MB)
    int* counts = (int*)d_ws;
    int* head = counts + (size_t)B * T;
    int* rp = head + (size_t)B * T;
    int* perm = rp + (size_t)B * RPS;
    size_t need = ((size_t)B * T * 2 + (size_t)B * RPS + (size_t)B * N) * 4;

    hemp_zero_kernel<<<(B * T / 4 + 255) / 256, 256, 0, stream>>>(counts);
    hemp_count_kernel<<<(B * N / 4 + 255) / 256, 256, 0, stream>>>(gid, counts);

    if (ws_size >= need) {
        hemp_scan_kernel<<<B, 1024, 0, stream>>>(counts, rp, head);
        hemp_fill_kernel<<<(B * N / 4 + 255) / 256, 256, 0, stream>>>(gid, head, perm);
        const int fused_lds = 161920;  // 40960*2 + 40000*2 bytes
        hipFuncSetAttribute(reinterpret_cast<const void*>(hemp_fused_kernel),
                            hipFuncAttributeMaxDynamicSharedMemorySize, fused_lds);
        hemp_fused_kernel<<<B * C, 512, fused_lds, stream>>>(feat, perm, rp, out);
    } else {
        const size_t lds_bytes = (size_t)T * sizeof(float);
        hipFuncSetAttribute(reinterpret_cast<const void*>(hemp_atomic_kernel),
                            hipFuncAttributeMaxDynamicSharedMemorySize, (int)lds_bytes);
        hemp_atomic_kernel<<<B * C, BLK, lds_bytes, stream>>>(feat, gid, counts, out);
    }
}

// Round 8
// 199.461 us; speedup vs baseline: 1.7998x; 1.7998x over previous
//
#include <hip/hip_runtime.h>

// HalfEdgeMeshPool: segment-mean over groups.
// feat: [B, C, N] f32, gid: [B, N] i32 in [0,T), out: [B, C, T] f32.
//
// R1/R2: LDS f32 atomics serialize ~3.2 cyc/lane -> 428us floor.
// R3: random 4B global gather = 14.5x line over-fetch -> 1.7ms.
// R5/R6: sort+transpose pipeline -> 250us (820MB traffic, 2 passes over feat-sized data).
// R7: single-pass fused (row in LDS, 160KB) -> 318us: 1 block/CU, 3 serialized
//     phases -> HBM idle during LDS phases, latency-under-subscribed streaming.
// R8: keep single-pass structure, fix concurrency. Padded member-table mt[t][8]
//     (u16, sentinel->zeroed LDS slot) replaces CSR+permute: phase 3 is uniform
//     (16B coalesced mt load + 8 LDS gathers), no scan kernel, LDS = 80KB row
//     only -> 2 blocks/CU overlap (one streams HBM while other gathers).
//     Rare groups (count>8, ~5 per mesh) via overflow list + tiny epilogue.
static constexpr int B = 8;
static constexpr int C = 256;
static constexpr int N = 40000;
static constexpr int T = 20000;
static constexpr int PAD = 8;                  // mt slots per group
static constexpr int MAXH = N / (PAD + 1) + 8; // heavy-group cap per b (pigeonhole)
static constexpr int LDSU = 40448;             // row_bf u16 slots (data + zero pad)

typedef float  f32x4 __attribute__((ext_vector_type(4)));
typedef ushort u16x4 __attribute__((ext_vector_type(4)));
typedef ushort u16x8 __attribute__((ext_vector_type(8)));

__device__ __forceinline__ ushort f2bf(float v) {
    unsigned u = __float_as_uint(v);
    u += 0x7FFFu + ((u >> 16) & 1u);  // round-to-nearest-even
    return (ushort)(u >> 16);
}
__device__ __forceinline__ float bf2f(ushort u) {
    return __uint_as_float((unsigned)u << 16);
}

// ---- init: head=0, mt=sentinel(40000=0x9C40), hcnt=ocnt=0 ----
__global__ void __launch_bounds__(256) hemp_init_kernel(int* __restrict__ head,
                                                        unsigned* __restrict__ mt32,
                                                        int* __restrict__ hcnt,
                                                        int* __restrict__ ocnt) {
    const int stride = gridDim.x * 256;
    int i = blockIdx.x * 256 + threadIdx.x;
    for (int k = i; k < B * T * PAD / 2; k += stride) mt32[k] = 0x9C409C40u;
    for (int k = i; k < B * T; k += stride) head[k] = 0;
    if (i < B) { hcnt[i] = 0; ocnt[i] = 0; }
}

// ---- fill: rank within group -> mt slot; count>PAD members -> overflow list ----
__global__ void __launch_bounds__(256) hemp_fill_kernel(const int* __restrict__ gid,
                                                        int* __restrict__ head,
                                                        ushort* __restrict__ mt,
                                                        unsigned* __restrict__ of,
                                                        int* __restrict__ hg,
                                                        int* __restrict__ hcnt,
                                                        int* __restrict__ ocnt) {
    int idx = blockIdx.x * 256 + threadIdx.x;
    if (idx >= B * N) return;
    int b = idx / N;
    int n = idx - b * N;
    int g = gid[idx];
    int r = atomicAdd(&head[b * T + g], 1);  // head ends as per-group count
    if (r < PAD) {
        mt[((size_t)(b * T + g)) * PAD + r] = (ushort)n;
    } else {
        int o = atomicAdd(&ocnt[b], 1);
        of[(size_t)b * N + o] = ((unsigned)g << 16) | (unsigned)n;
        if (r == PAD) {  // first overflow: register g as heavy
            int h = atomicAdd(&hcnt[b], 1);
            hg[b * MAXH + h] = g;
        }
    }
}

// ---- fused: one block per (b,c). Stream row->LDS bf16; uniform 8-gather per t ----
__global__ void __launch_bounds__(512) hemp_fused_kernel(const float* __restrict__ feat,
                                                         const ushort* __restrict__ mt,
                                                         const int* __restrict__ head,
                                                         const unsigned* __restrict__ of,
                                                         const int* __restrict__ hg,
                                                         const int* __restrict__ hcnt,
                                                         const int* __restrict__ ocnt,
                                                         float* __restrict__ out) {
    extern __shared__ ushort row_bf[];  // LDSU u16 = 80896 B -> 2 blocks/CU
    const int tid = threadIdx.x;
    const int b = blockIdx.x >> 8;  // same-b blocks adjacent -> mt/cnt L2-hot
    const int c = blockIdx.x & 255;

    // zero the pad region (sentinel 40000 lands here)
    if (tid < (LDSU - N) / 4)
        *reinterpret_cast<u16x4*>(&row_bf[N + tid * 4]) = (u16x4){0, 0, 0, 0};

    // Phase 1: stream feature row into LDS as bf16 (unroll-2 for load depth)
    const f32x4* __restrict__ f4 =
        reinterpret_cast<const f32x4*>(feat + (size_t)(b * C + c) * N);
    for (int i = tid; i < N / 4; i += 1024) {
        f32x4 v0 = __builtin_nontemporal_load(f4 + i);
        const int i2 = i + 512;
        const bool ok = i2 < N / 4;
        f32x4 v1 = {};
        if (ok) v1 = __builtin_nontemporal_load(f4 + i2);
        u16x4 w0 = {f2bf(v0.x), f2bf(v0.y), f2bf(v0.z), f2bf(v0.w)};
        *reinterpret_cast<u16x4*>(&row_bf[i * 4]) = w0;
        if (ok) {
            u16x4 w1 = {f2bf(v1.x), f2bf(v1.y), f2bf(v1.z), f2bf(v1.w)};
            *reinterpret_cast<u16x4*>(&row_bf[i2 * 4]) = w1;
        }
    }
    __syncthreads();

    // Phase 2: uniform gather-sum. 16B coalesced mt load + 8 LDS u16 gathers.
    const ushort* __restrict__ mtb = mt + (size_t)b * T * PAD;
    const int* __restrict__ cntb = head + b * T;
    float* __restrict__ orow = out + (size_t)(b * C + c) * T;
    for (int t = tid; t < T; t += 512) {
        u16x8 m = *reinterpret_cast<const u16x8*>(mtb + (size_t)t * PAD);
        int cnt = cntb[t];
        float s = ((bf2f(row_bf[m[0]]) + bf2f(row_bf[m[1]])) +
                   (bf2f(row_bf[m[2]]) + bf2f(row_bf[m[3]]))) +
                  ((bf2f(row_bf[m[4]]) + bf2f(row_bf[m[5]])) +
                   (bf2f(row_bf[m[6]]) + bf2f(row_bf[m[7]])));
        if (cnt <= PAD)
            __builtin_nontemporal_store(s / fmaxf((float)cnt, 1.0f), orow + t);
    }

    // Epilogue: heavy groups (count>PAD, rare) — 8 mt slots + overflow scan
    const int H = hcnt[b];
    if (H > 0) {
        const int O = ocnt[b];
        const unsigned* __restrict__ ofb = of + (size_t)b * N;
        for (int i = tid; i < H; i += 512) {
            const int g = hg[b * MAXH + i];
            const ushort* mg = mtb + (size_t)g * PAD;
            float s = 0.0f;
            #pragma unroll
            for (int k = 0; k < PAD; ++k) s += bf2f(row_bf[mg[k]]);
            for (int e = 0; e < O; ++e) {
                unsigned w = ofb[e];
                if ((w >> 16) == (unsigned)g) s += bf2f(row_bf[w & 0xFFFFu]);
            }
            orow[g] = s / (float)cntb[g];
        }
    }
}

// ---- fallback (ws too small): R2 LDS-atomic kernel ----
static constexpr int BLK = 1024;
__global__ void __launch_bounds__(256) hemp_count_kernel(const int* __restrict__ gid,
                                                         int* __restrict__ counts) {
    int idx = blockIdx.x * 256 + threadIdx.x;
    if (idx < B * N) {
        int b = idx / N;
        atomicAdd(&counts[b * T + gid[idx]], 1);
    }
}
__global__ void __launch_bounds__(BLK) hemp_atomic_kernel(const float* __restrict__ feat,
                                                          const int* __restrict__ gid,
                                                          const int* __restrict__ counts,
                                                          float* __restrict__ out) {
    extern __shared__ float lds_sum[];
    const int tid = threadIdx.x;
    const int b = blockIdx.x >> 8;
    const int c = blockIdx.x & 255;
    float4* ls4 = reinterpret_cast<float4*>(lds_sum);
    for (int t = tid; t < T / 4; t += BLK) ls4[t] = make_float4(0.f, 0.f, 0.f, 0.f);
    __syncthreads();
    const float4* f4 = reinterpret_cast<const float4*>(feat + (size_t)(b * C + c) * N);
    const int4* g4 = reinterpret_cast<const int4*>(gid + (size_t)b * N);
    for (int i = tid; i < N / 4; i += BLK) {
        float4 v = f4[i];
        int4 g = g4[i];
        unsafeAtomicAdd(&lds_sum[g.x], v.x);
        unsafeAtomicAdd(&lds_sum[g.y], v.y);
        unsafeAtomicAdd(&lds_sum[g.z], v.z);
        unsafeAtomicAdd(&lds_sum[g.w], v.w);
    }
    __syncthreads();
    const int4* cnt4 = reinterpret_cast<const int4*>(counts + (size_t)b * T);
    float4* out4 = reinterpret_cast<float4*>(out + (size_t)(b * C + c) * T);
    for (int t = tid; t < T / 4; t += BLK) {
        int4 cn = cnt4[t];
        float4 s = ls4[t];
        float4 r;
        r.x = s.x / fmaxf((float)cn.x, 1.0f);
        r.y = s.y / fmaxf((float)cn.y, 1.0f);
        r.z = s.z / fmaxf((float)cn.z, 1.0f);
        r.w = s.w / fmaxf((float)cn.w, 1.0f);
        out4[t] = r;
    }
}

extern "C" void kernel_launch(void* const* d_in, const int* in_sizes, int n_in,
                              void* d_out, int out_size, void* d_ws, size_t ws_size,
                              hipStream_t stream) {
    const float* feat = (const float*)d_in[0];
    const int* gid = (const int*)d_in[1];
    float* out = (float*)d_out;

    // ws: head[B*T] i32 | mt[B*T*PAD] u16 | of[B*N] u32 | hg[B*MAXH] i32 | hcnt[B] | ocnt[B]
    char* p = (char*)d_ws;
    int* head = (int*)p;            p += (size_t)B * T * 4;
    ushort* mt = (ushort*)p;        p += (size_t)B * T * PAD * 2;
    unsigned* of = (unsigned*)p;    p += (size_t)B * N * 4;
    int* hg = (int*)p;              p += (size_t)B * MAXH * 4;
    int* hcnt = (int*)p;            p += (size_t)B * 4;
    int* ocnt = (int*)p;            p += (size_t)B * 4;
    size_t need = (size_t)(p - (char*)d_ws);

    if (ws_size >= need) {
        hemp_init_kernel<<<2560, 256, 0, stream>>>(head, (unsigned*)mt, hcnt, ocnt);
        hemp_fill_kernel<<<(B * N + 255) / 256, 256, 0, stream>>>(gid, head, mt, of,
                                                                  hg, hcnt, ocnt);
        const int lds_bytes = LDSU * 2;  // 80896 B -> 2 blocks/CU
        hipFuncSetAttribute(reinterpret_cast<const void*>(hemp_fused_kernel),
                            hipFuncAttributeMaxDynamicSharedMemorySize, lds_bytes);
        hemp_fused_kernel<<<B * C, 512, lds_bytes, stream>>>(feat, mt, head, of, hg,
                                                             hcnt, ocnt, out);
    } else {
        int* counts = (int*)d_ws;  // needs only 640 KB
        hemp_init_kernel<<<2560, 256, 0, stream>>>(counts, (unsigned*)(counts + B * T / 2),
                                                   counts, counts);  // zeros counts region
        hemp_count_kernel<<<(B * N + 255) / 256, 256, 0, stream>>>(gid, counts);
        const size_t lds_bytes = (size_t)T * sizeof(float);
        hipFuncSetAttribute(reinterpret_cast<const void*>(hemp_atomic_kernel),
                            hipFuncAttributeMaxDynamicSharedMemorySize, (int)lds_bytes);
        hemp_atomic_kernel<<<B * C, BLK, lds_bytes, stream>>>(feat, gid, counts, out);
    }
}